// Round 2
// baseline (1493.355 us; speedup 1.0000x reference)
//
#include <hip/hip_runtime.h>

#define N_NODES 50000
#define N_EDGES 800000
#define IN_CH   64
#define OUT_CH  128
#define FEAT    192   // IN_CH * 3 powers

// ---------------------------------------------------------------------------
// scatter_add: h_out[dst] += h_in[src] over all edges.
// 16 threads per edge, each handles 4 consecutive channels (float4 gather,
// 4 scalar f32 atomics). edge_index layout is [2, E] row-major:
// src = ei[e], dst = ei[N_EDGES + e].
// ---------------------------------------------------------------------------
__global__ __launch_bounds__(256) void scatter_add_kernel(
    const float* __restrict__ hin, const int* __restrict__ ei,
    float* __restrict__ hout) {
  const int gid = blockIdx.x * blockDim.x + threadIdx.x;
  const int e = gid >> 4;
  if (e >= N_EDGES) return;
  const int c = (gid & 15) << 2;
  const int s = ei[e];
  const int d = ei[N_EDGES + e];
  const float4 v =
      *reinterpret_cast<const float4*>(hin + (size_t)s * IN_CH + c);
  float* p = hout + (size_t)d * IN_CH + c;
  atomicAdd(p + 0, v.x);
  atomicAdd(p + 1, v.y);
  atomicAdd(p + 2, v.z);
  atomicAdd(p + 3, v.w);
}

// ---------------------------------------------------------------------------
// W [OUT_CH, FEAT] -> Wt [FEAT, OUT_CH] so the GEMM's per-k W loads are
// lane-coalesced (lane o reads Wt[k*128 + o]).
// ---------------------------------------------------------------------------
__global__ __launch_bounds__(256) void transpose_w_kernel(
    const float* __restrict__ W, float* __restrict__ Wt) {
  const int i = blockIdx.x * blockDim.x + threadIdx.x;
  if (i >= OUT_CH * FEAT) return;
  const int o = i / FEAT;
  const int k = i - o * FEAT;
  Wt[k * OUT_CH + o] = W[i];
}

// ---------------------------------------------------------------------------
// out[n, o] = b[o] + sum_k feats[n, k] * W[o, k]
// feats[n] = [x[n] | h1[n] | h2[n]]   (never materialized in global)
// Block: 256 threads, 16 nodes. LDS feats tile 16x192 f32 (12 KB).
// Thread (o = tid&127, g = tid>>7) computes 8 nodes' outputs for channel o.
// ---------------------------------------------------------------------------
__global__ __launch_bounds__(256) void gemm_kernel(
    const float* __restrict__ x, const float* __restrict__ h1,
    const float* __restrict__ h2, const float* __restrict__ Wt,
    const float* __restrict__ b, float* __restrict__ out) {
  __shared__ float sf[16][FEAT];

  const int tid = threadIdx.x;
  const int node0 = blockIdx.x * 16;

  // Stage feats: each thread loads one float4 per source array.
  {
    const int node = tid >> 4;       // 0..15
    const int q = (tid & 15) << 2;   // 0,4,...,60
    const size_t row = (size_t)(node0 + node) * IN_CH + q;
    const float4 vx = *reinterpret_cast<const float4*>(x + row);
    const float4 v1 = *reinterpret_cast<const float4*>(h1 + row);
    const float4 v2 = *reinterpret_cast<const float4*>(h2 + row);
    sf[node][q + 0] = vx.x; sf[node][q + 1] = vx.y;
    sf[node][q + 2] = vx.z; sf[node][q + 3] = vx.w;
    sf[node][IN_CH + q + 0] = v1.x; sf[node][IN_CH + q + 1] = v1.y;
    sf[node][IN_CH + q + 2] = v1.z; sf[node][IN_CH + q + 3] = v1.w;
    sf[node][2 * IN_CH + q + 0] = v2.x; sf[node][2 * IN_CH + q + 1] = v2.y;
    sf[node][2 * IN_CH + q + 2] = v2.z; sf[node][2 * IN_CH + q + 3] = v2.w;
  }
  __syncthreads();

  const int o = tid & 127;
  const int g = tid >> 7;  // node group 0/1
  float acc[8];
#pragma unroll
  for (int i = 0; i < 8; ++i) acc[i] = 0.0f;
  const float bias = b[o];

  for (int k = 0; k < FEAT; k += 4) {
    const float w0 = Wt[(k + 0) * OUT_CH + o];
    const float w1 = Wt[(k + 1) * OUT_CH + o];
    const float w2 = Wt[(k + 2) * OUT_CH + o];
    const float w3 = Wt[(k + 3) * OUT_CH + o];
#pragma unroll
    for (int i = 0; i < 8; ++i) {
      const int n = g * 8 + i;
      const float4 f = *reinterpret_cast<const float4*>(&sf[n][k]);
      acc[i] = fmaf(f.x, w0, acc[i]);
      acc[i] = fmaf(f.y, w1, acc[i]);
      acc[i] = fmaf(f.z, w2, acc[i]);
      acc[i] = fmaf(f.w, w3, acc[i]);
    }
  }

#pragma unroll
  for (int i = 0; i < 8; ++i) {
    const int n = g * 8 + i;
    out[(size_t)(node0 + n) * OUT_CH + o] = acc[i] + bias;
  }
}

extern "C" void kernel_launch(void* const* d_in, const int* in_sizes, int n_in,
                              void* d_out, int out_size, void* d_ws,
                              size_t ws_size, hipStream_t stream) {
  const float* x = (const float*)d_in[0];
  const int* ei = (const int*)d_in[1];   // [2, N_EDGES], int32 per harness
  const float* W = (const float*)d_in[2];
  const float* b = (const float*)d_in[3];
  float* out = (float*)d_out;

  // Workspace layout: h1 | h2 | Wt
  float* h1 = (float*)d_ws;
  float* h2 = h1 + (size_t)N_NODES * IN_CH;
  float* Wt = h2 + (size_t)N_NODES * IN_CH;

  // Zero h1 and h2 (ws is poisoned to 0xAA before every call).
  hipMemsetAsync(d_ws, 0, (size_t)2 * N_NODES * IN_CH * sizeof(float), stream);

  // Transpose W for coalesced GEMM loads.
  transpose_w_kernel<<<(OUT_CH * FEAT + 255) / 256, 256, 0, stream>>>(W, Wt);

  // Hop 1: h1[dst] += x[src]
  const int scatter_threads = N_EDGES * 16;
  const int scatter_blocks = (scatter_threads + 255) / 256;
  scatter_add_kernel<<<scatter_blocks, 256, 0, stream>>>(x, ei, h1);

  // Hop 2: h2[dst] += h1[src]
  scatter_add_kernel<<<scatter_blocks, 256, 0, stream>>>(h1, ei, h2);

  // out = [x|h1|h2] @ W.T + b
  gemm_kernel<<<N_NODES / 16, 256, 0, stream>>>(x, h1, h2, Wt, b, out);
}

// Round 3
// 411.789 us; speedup vs baseline: 3.6265x; 3.6265x over previous
//
#include <hip/hip_runtime.h>

#define N_NODES 50000
#define N_EDGES 800000
#define IN_CH   64
#define OUT_CH  128
#define FEAT    192   // IN_CH * 3 powers

// ---------------------------------------------------------------------------
// CSR build step 1: histogram of destination nodes.
// ---------------------------------------------------------------------------
__global__ __launch_bounds__(256) void hist_kernel(const int* __restrict__ ei,
                                                   int* __restrict__ counts) {
  const int e = blockIdx.x * blockDim.x + threadIdx.x;
  if (e >= N_EDGES) return;
  atomicAdd(&counts[ei[N_EDGES + e]], 1);
}

// ---------------------------------------------------------------------------
// CSR build step 2: single-block exclusive scan of counts[0..N_NODES) into
// rowptr[0..N_NODES] and cursor[0..N_NODES). 1024 threads, ~49 elems each.
// ---------------------------------------------------------------------------
__global__ __launch_bounds__(1024) void scan_kernel(
    const int* __restrict__ counts, int* __restrict__ rowptr,
    int* __restrict__ cursor) {
  __shared__ int part[1024];
  const int t = threadIdx.x;
  const int C = (N_NODES + 1023) / 1024;  // 49
  const int lo = t * C;
  const int hi = (lo + C < N_NODES) ? lo + C : N_NODES;

  int sum = 0;
  for (int i = lo; i < hi; ++i) sum += counts[i];
  part[t] = sum;
  __syncthreads();

  // Hillis-Steele inclusive scan over the 1024 partials.
  for (int off = 1; off < 1024; off <<= 1) {
    int v = (t >= off) ? part[t - off] : 0;
    __syncthreads();
    part[t] += v;
    __syncthreads();
  }

  int run = part[t] - sum;  // exclusive offset for this thread's chunk
  for (int i = lo; i < hi; ++i) {
    rowptr[i] = run;
    cursor[i] = run;
    run += counts[i];
  }
  if (t == 1023) rowptr[N_NODES] = part[1023];
}

// ---------------------------------------------------------------------------
// CSR build step 3: place each edge's src into its dst bucket.
// ---------------------------------------------------------------------------
__global__ __launch_bounds__(256) void fill_kernel(const int* __restrict__ ei,
                                                   int* __restrict__ cursor,
                                                   int* __restrict__ srcs) {
  const int e = blockIdx.x * blockDim.x + threadIdx.x;
  if (e >= N_EDGES) return;
  const int d = ei[N_EDGES + e];
  const int pos = atomicAdd(&cursor[d], 1);
  srcs[pos] = ei[e];
}

// ---------------------------------------------------------------------------
// Gather hop: hout[n][c] = sum over in-edges(n) of hin[src][c].
// One wave per node, lane = channel (IN_CH == 64 == wavefront).
// Row reads are 64 lanes x 4B = 256B contiguous; source array is
// L2/L3-resident (12.8 MB). No atomics, no pre-zeroing needed.
// ---------------------------------------------------------------------------
__global__ __launch_bounds__(256) void gather_kernel(
    const float* __restrict__ hin, const int* __restrict__ rowptr,
    const int* __restrict__ srcs, float* __restrict__ hout) {
  const int gid = blockIdx.x * blockDim.x + threadIdx.x;
  const int node = gid >> 6;
  if (node >= N_NODES) return;
  const int lane = threadIdx.x & 63;

  const int beg = rowptr[node];
  const int end = rowptr[node + 1];

  float acc0 = 0.0f, acc1 = 0.0f;
  int i = beg;
  for (; i + 1 < end; i += 2) {  // 2 independent row loads in flight
    const int s0 = srcs[i];
    const int s1 = srcs[i + 1];
    acc0 += hin[(size_t)s0 * IN_CH + lane];
    acc1 += hin[(size_t)s1 * IN_CH + lane];
  }
  if (i < end) acc0 += hin[(size_t)srcs[i] * IN_CH + lane];

  hout[(size_t)node * IN_CH + lane] = acc0 + acc1;
}

// ---------------------------------------------------------------------------
// W [OUT_CH, FEAT] -> Wt [FEAT, OUT_CH] for coalesced GEMM loads.
// ---------------------------------------------------------------------------
__global__ __launch_bounds__(256) void transpose_w_kernel(
    const float* __restrict__ W, float* __restrict__ Wt) {
  const int i = blockIdx.x * blockDim.x + threadIdx.x;
  if (i >= OUT_CH * FEAT) return;
  const int o = i / FEAT;
  const int k = i - o * FEAT;
  Wt[k * OUT_CH + o] = W[i];
}

// ---------------------------------------------------------------------------
// out[n, o] = b[o] + sum_k feats[n, k] * W[o, k],  feats = [x | h1 | h2]
// Block: 256 threads, 16 nodes staged in LDS (16x192 f32).
// ---------------------------------------------------------------------------
__global__ __launch_bounds__(256) void gemm_kernel(
    const float* __restrict__ x, const float* __restrict__ h1,
    const float* __restrict__ h2, const float* __restrict__ Wt,
    const float* __restrict__ b, float* __restrict__ out) {
  __shared__ float sf[16][FEAT];

  const int tid = threadIdx.x;
  const int node0 = blockIdx.x * 16;

  {
    const int node = tid >> 4;       // 0..15
    const int q = (tid & 15) << 2;   // 0,4,...,60
    const size_t row = (size_t)(node0 + node) * IN_CH + q;
    const float4 vx = *reinterpret_cast<const float4*>(x + row);
    const float4 v1 = *reinterpret_cast<const float4*>(h1 + row);
    const float4 v2 = *reinterpret_cast<const float4*>(h2 + row);
    sf[node][q + 0] = vx.x; sf[node][q + 1] = vx.y;
    sf[node][q + 2] = vx.z; sf[node][q + 3] = vx.w;
    sf[node][IN_CH + q + 0] = v1.x; sf[node][IN_CH + q + 1] = v1.y;
    sf[node][IN_CH + q + 2] = v1.z; sf[node][IN_CH + q + 3] = v1.w;
    sf[node][2 * IN_CH + q + 0] = v2.x; sf[node][2 * IN_CH + q + 1] = v2.y;
    sf[node][2 * IN_CH + q + 2] = v2.z; sf[node][2 * IN_CH + q + 3] = v2.w;
  }
  __syncthreads();

  const int o = tid & 127;
  const int g = tid >> 7;
  float acc[8];
#pragma unroll
  for (int i = 0; i < 8; ++i) acc[i] = 0.0f;
  const float bias = b[o];

  for (int k = 0; k < FEAT; k += 4) {
    const float w0 = Wt[(k + 0) * OUT_CH + o];
    const float w1 = Wt[(k + 1) * OUT_CH + o];
    const float w2 = Wt[(k + 2) * OUT_CH + o];
    const float w3 = Wt[(k + 3) * OUT_CH + o];
#pragma unroll
    for (int i = 0; i < 8; ++i) {
      const int n = g * 8 + i;
      const float4 f = *reinterpret_cast<const float4*>(&sf[n][k]);
      acc[i] = fmaf(f.x, w0, acc[i]);
      acc[i] = fmaf(f.y, w1, acc[i]);
      acc[i] = fmaf(f.z, w2, acc[i]);
      acc[i] = fmaf(f.w, w3, acc[i]);
    }
  }

#pragma unroll
  for (int i = 0; i < 8; ++i) {
    const int n = g * 8 + i;
    out[(size_t)(node0 + n) * OUT_CH + o] = acc[i] + bias;
  }
}

extern "C" void kernel_launch(void* const* d_in, const int* in_sizes, int n_in,
                              void* d_out, int out_size, void* d_ws,
                              size_t ws_size, hipStream_t stream) {
  const float* x = (const float*)d_in[0];
  const int* ei = (const int*)d_in[1];   // [2, N_EDGES], int32 per harness
  const float* W = (const float*)d_in[2];
  const float* b = (const float*)d_in[3];
  float* out = (float*)d_out;

  // Workspace layout: h1 | h2 | Wt | counts | rowptr | cursor | srcs
  float* h1 = (float*)d_ws;
  float* h2 = h1 + (size_t)N_NODES * IN_CH;
  float* Wt = h2 + (size_t)N_NODES * IN_CH;
  int* counts = (int*)(Wt + FEAT * OUT_CH);
  int* rowptr = counts + N_NODES;
  int* cursor = rowptr + (N_NODES + 1);
  int* srcs = cursor + N_NODES;

  // Zero only the histogram bins (ws is poisoned to 0xAA before every call).
  hipMemsetAsync(counts, 0, N_NODES * sizeof(int), stream);

  const int eblocks = (N_EDGES + 255) / 256;

  // Build by-destination CSR (int atomics only).
  hist_kernel<<<eblocks, 256, 0, stream>>>(ei, counts);
  scan_kernel<<<1, 1024, 0, stream>>>(counts, rowptr, cursor);
  fill_kernel<<<eblocks, 256, 0, stream>>>(ei, cursor, srcs);

  // Transpose W for coalesced GEMM loads.
  transpose_w_kernel<<<(OUT_CH * FEAT + 255) / 256, 256, 0, stream>>>(W, Wt);

  // Hop 1: h1 = gather(x); Hop 2: h2 = gather(h1). One wave per node.
  const int gblocks = (N_NODES * 64 + 255) / 256;
  gather_kernel<<<gblocks, 256, 0, stream>>>(x, rowptr, srcs, h1);
  gather_kernel<<<gblocks, 256, 0, stream>>>(h1, rowptr, srcs, h2);

  // out = [x|h1|h2] @ W.T + b
  gemm_kernel<<<N_NODES / 16, 256, 0, stream>>>(x, h1, h2, Wt, b, out);
}

// Round 4
// 284.617 us; speedup vs baseline: 5.2469x; 1.4468x over previous
//
#include <hip/hip_runtime.h>

#define N_NODES 50000
#define N_EDGES 800000
#define IN_CH   64
#define OUT_CH  128
#define FEAT    192   // IN_CH * 3 powers
#define NBLK_SCAN ((N_NODES + 255) / 256)  // 196

// ---------------------------------------------------------------------------
// CSR build step 1: histogram of destination nodes (int atomics).
// ---------------------------------------------------------------------------
__global__ __launch_bounds__(256) void hist_kernel(const int* __restrict__ ei,
                                                   int* __restrict__ counts) {
  const int e = blockIdx.x * blockDim.x + threadIdx.x;
  if (e >= N_EDGES) return;
  atomicAdd(&counts[ei[N_EDGES + e]], 1);
}

// ---------------------------------------------------------------------------
// CSR build step 2a: per-block exclusive scan (256 elems) + block totals.
// ---------------------------------------------------------------------------
__global__ __launch_bounds__(256) void scan_block_kernel(
    const int* __restrict__ counts, int* __restrict__ prescan,
    int* __restrict__ blocksums) {
  __shared__ int sdata[256];
  const int tid = threadIdx.x;
  const int gid = blockIdx.x * 256 + tid;
  const int v = (gid < N_NODES) ? counts[gid] : 0;
  sdata[tid] = v;
  __syncthreads();
  for (int off = 1; off < 256; off <<= 1) {
    const int t = (tid >= off) ? sdata[tid - off] : 0;
    __syncthreads();
    sdata[tid] += t;
    __syncthreads();
  }
  if (gid < N_NODES) prescan[gid] = sdata[tid] - v;  // exclusive
  if (tid == 255) blocksums[blockIdx.x] = sdata[255];
}

// ---------------------------------------------------------------------------
// CSR build step 2b: add block offsets; emit rowptr and cursor.
// Each block reduces blocksums[0..bid) itself (<=196 L2-hit loads).
// ---------------------------------------------------------------------------
__global__ __launch_bounds__(256) void scan_finalize_kernel(
    const int* __restrict__ prescan, const int* __restrict__ blocksums,
    int* __restrict__ rowptr, int* __restrict__ cursor) {
  __shared__ int sred[256];
  const int tid = threadIdx.x;
  int part = 0;
  for (int j = tid; j < blockIdx.x; j += 256) part += blocksums[j];
  sred[tid] = part;
  __syncthreads();
  for (int s = 128; s > 0; s >>= 1) {
    if (tid < s) sred[tid] += sred[tid + s];
    __syncthreads();
  }
  const int boff = sred[0];
  const int gid = blockIdx.x * 256 + tid;
  if (gid < N_NODES) {
    const int r = boff + prescan[gid];
    rowptr[gid] = r;
    cursor[gid] = r;
  }
  if (gid == 0) rowptr[N_NODES] = N_EDGES;  // total is a compile-time constant
}

// ---------------------------------------------------------------------------
// CSR build step 3: place each edge's src into its dst bucket.
// ---------------------------------------------------------------------------
__global__ __launch_bounds__(256) void fill_kernel(const int* __restrict__ ei,
                                                   int* __restrict__ cursor,
                                                   int* __restrict__ srcs) {
  const int e = blockIdx.x * blockDim.x + threadIdx.x;
  if (e >= N_EDGES) return;
  const int d = ei[N_EDGES + e];
  const int pos = atomicAdd(&cursor[d], 1);
  srcs[pos] = ei[e];
}

// ---------------------------------------------------------------------------
// Gather hop: hout[n][c] = sum over in-edges(n) of hin[src][c].
// One wave per node, lane = channel. 4 independent 256B row loads in flight.
// ---------------------------------------------------------------------------
__global__ __launch_bounds__(256) void gather_kernel(
    const float* __restrict__ hin, const int* __restrict__ rowptr,
    const int* __restrict__ srcs, float* __restrict__ hout) {
  const int gid = blockIdx.x * blockDim.x + threadIdx.x;
  const int node = gid >> 6;
  if (node >= N_NODES) return;
  const int lane = threadIdx.x & 63;

  const int beg = rowptr[node];
  const int end = rowptr[node + 1];

  float acc0 = 0.0f, acc1 = 0.0f, acc2 = 0.0f, acc3 = 0.0f;
  int i = beg;
  for (; i + 3 < end; i += 4) {
    const int s0 = srcs[i], s1 = srcs[i + 1], s2 = srcs[i + 2],
              s3 = srcs[i + 3];
    acc0 += hin[(size_t)s0 * IN_CH + lane];
    acc1 += hin[(size_t)s1 * IN_CH + lane];
    acc2 += hin[(size_t)s2 * IN_CH + lane];
    acc3 += hin[(size_t)s3 * IN_CH + lane];
  }
  for (; i < end; ++i) acc0 += hin[(size_t)srcs[i] * IN_CH + lane];

  hout[(size_t)node * IN_CH + lane] = (acc0 + acc1) + (acc2 + acc3);
}

// ---------------------------------------------------------------------------
// W [OUT_CH, FEAT] -> Wt [FEAT, OUT_CH] for coalesced GEMM loads.
// ---------------------------------------------------------------------------
__global__ __launch_bounds__(256) void transpose_w_kernel(
    const float* __restrict__ W, float* __restrict__ Wt) {
  const int i = blockIdx.x * blockDim.x + threadIdx.x;
  if (i >= OUT_CH * FEAT) return;
  const int o = i / FEAT;
  const int k = i - o * FEAT;
  Wt[k * OUT_CH + o] = W[i];
}

// ---------------------------------------------------------------------------
// out[n, o] = b[o] + sum_k feats[n, k] * W[o, k],  feats = [x | h1 | h2]
// Block: 256 threads, 16 nodes staged in LDS (16x192 f32).
// ---------------------------------------------------------------------------
__global__ __launch_bounds__(256) void gemm_kernel(
    const float* __restrict__ x, const float* __restrict__ h1,
    const float* __restrict__ h2, const float* __restrict__ Wt,
    const float* __restrict__ b, float* __restrict__ out) {
  __shared__ float sf[16][FEAT];

  const int tid = threadIdx.x;
  const int node0 = blockIdx.x * 16;

  {
    const int node = tid >> 4;       // 0..15
    const int q = (tid & 15) << 2;   // 0,4,...,60
    const size_t row = (size_t)(node0 + node) * IN_CH + q;
    const float4 vx = *reinterpret_cast<const float4*>(x + row);
    const float4 v1 = *reinterpret_cast<const float4*>(h1 + row);
    const float4 v2 = *reinterpret_cast<const float4*>(h2 + row);
    sf[node][q + 0] = vx.x; sf[node][q + 1] = vx.y;
    sf[node][q + 2] = vx.z; sf[node][q + 3] = vx.w;
    sf[node][IN_CH + q + 0] = v1.x; sf[node][IN_CH + q + 1] = v1.y;
    sf[node][IN_CH + q + 2] = v1.z; sf[node][IN_CH + q + 3] = v1.w;
    sf[node][2 * IN_CH + q + 0] = v2.x; sf[node][2 * IN_CH + q + 1] = v2.y;
    sf[node][2 * IN_CH + q + 2] = v2.z; sf[node][2 * IN_CH + q + 3] = v2.w;
  }
  __syncthreads();

  const int o = tid & 127;
  const int g = tid >> 7;
  float acc[8];
#pragma unroll
  for (int i = 0; i < 8; ++i) acc[i] = 0.0f;
  const float bias = b[o];

  for (int k = 0; k < FEAT; k += 4) {
    const float w0 = Wt[(k + 0) * OUT_CH + o];
    const float w1 = Wt[(k + 1) * OUT_CH + o];
    const float w2 = Wt[(k + 2) * OUT_CH + o];
    const float w3 = Wt[(k + 3) * OUT_CH + o];
#pragma unroll
    for (int i = 0; i < 8; ++i) {
      const int n = g * 8 + i;
      const float4 f = *reinterpret_cast<const float4*>(&sf[n][k]);
      acc[i] = fmaf(f.x, w0, acc[i]);
      acc[i] = fmaf(f.y, w1, acc[i]);
      acc[i] = fmaf(f.z, w2, acc[i]);
      acc[i] = fmaf(f.w, w3, acc[i]);
    }
  }

#pragma unroll
  for (int i = 0; i < 8; ++i) {
    const int n = g * 8 + i;
    out[(size_t)(node0 + n) * OUT_CH + o] = acc[i] + bias;
  }
}

extern "C" void kernel_launch(void* const* d_in, const int* in_sizes, int n_in,
                              void* d_out, int out_size, void* d_ws,
                              size_t ws_size, hipStream_t stream) {
  const float* x = (const float*)d_in[0];
  const int* ei = (const int*)d_in[1];   // [2, N_EDGES], int32 per harness
  const float* W = (const float*)d_in[2];
  const float* b = (const float*)d_in[3];
  float* out = (float*)d_out;

  // Workspace layout: h1 | h2 | Wt | counts | rowptr | cursor | srcs |
  //                   prescan | blocksums
  float* h1 = (float*)d_ws;
  float* h2 = h1 + (size_t)N_NODES * IN_CH;
  float* Wt = h2 + (size_t)N_NODES * IN_CH;
  int* counts = (int*)(Wt + FEAT * OUT_CH);
  int* rowptr = counts + N_NODES;
  int* cursor = rowptr + (N_NODES + 1);
  int* srcs = cursor + N_NODES;
  int* prescan = srcs + N_EDGES;
  int* blocksums = prescan + N_NODES;

  // Zero only the histogram bins (ws is poisoned to 0xAA before every call).
  hipMemsetAsync(counts, 0, N_NODES * sizeof(int), stream);

  const int eblocks = (N_EDGES + 255) / 256;

  // Build by-destination CSR (int atomics only).
  hist_kernel<<<eblocks, 256, 0, stream>>>(ei, counts);
  scan_block_kernel<<<NBLK_SCAN, 256, 0, stream>>>(counts, prescan, blocksums);
  scan_finalize_kernel<<<NBLK_SCAN, 256, 0, stream>>>(prescan, blocksums,
                                                      rowptr, cursor);
  fill_kernel<<<eblocks, 256, 0, stream>>>(ei, cursor, srcs);

  // Transpose W for coalesced GEMM loads.
  transpose_w_kernel<<<(OUT_CH * FEAT + 255) / 256, 256, 0, stream>>>(W, Wt);

  // Hop 1: h1 = gather(x); Hop 2: h2 = gather(h1). One wave per node.
  const int gblocks = (N_NODES * 64 + 255) / 256;
  gather_kernel<<<gblocks, 256, 0, stream>>>(x, rowptr, srcs, h1);
  gather_kernel<<<gblocks, 256, 0, stream>>>(h1, rowptr, srcs, h2);

  // out = [x|h1|h2] @ W.T + b
  gemm_kernel<<<N_NODES / 16, 256, 0, stream>>>(x, h1, h2, Wt, b, out);
}

// Round 5
// 230.563 us; speedup vs baseline: 6.4770x; 1.2344x over previous
//
#include <hip/hip_runtime.h>

#define N_NODES 50000
#define N_EDGES 800000
#define IN_CH   64
#define OUT_CH  128
#define FEAT    192   // IN_CH * 3 powers
#define NBLK_SCAN ((N_NODES + 255) / 256)  // 196
#define N_TILES  (N_NODES / 16)            // 3125 wave-tiles for GEMM

typedef __attribute__((ext_vector_type(8))) short short8;  // 8 bf16 (4 VGPRs)
typedef __attribute__((ext_vector_type(4))) float f32x4;

static __device__ __forceinline__ unsigned short f2bf(float f) {
  // round-to-nearest-even f32 -> bf16 (finite inputs)
  unsigned int u = __float_as_uint(f);
  u += 0x7FFFu + ((u >> 16) & 1u);
  return (unsigned short)(u >> 16);
}
static __device__ __forceinline__ float bf2f(unsigned int s) {
  return __uint_as_float(s << 16);
}

// ---------------------------------------------------------------------------
// CSR build step 1: histogram of destination nodes (int atomics).
// ---------------------------------------------------------------------------
__global__ __launch_bounds__(256) void hist_kernel(const int* __restrict__ ei,
                                                   int* __restrict__ counts) {
  const int e = blockIdx.x * blockDim.x + threadIdx.x;
  if (e >= N_EDGES) return;
  atomicAdd(&counts[ei[N_EDGES + e]], 1);
}

// ---------------------------------------------------------------------------
// CSR build step 2a: per-block exclusive scan (256 elems) + block totals.
// ---------------------------------------------------------------------------
__global__ __launch_bounds__(256) void scan_block_kernel(
    const int* __restrict__ counts, int* __restrict__ prescan,
    int* __restrict__ blocksums) {
  __shared__ int sdata[256];
  const int tid = threadIdx.x;
  const int gid = blockIdx.x * 256 + tid;
  const int v = (gid < N_NODES) ? counts[gid] : 0;
  sdata[tid] = v;
  __syncthreads();
  for (int off = 1; off < 256; off <<= 1) {
    const int t = (tid >= off) ? sdata[tid - off] : 0;
    __syncthreads();
    sdata[tid] += t;
    __syncthreads();
  }
  if (gid < N_NODES) prescan[gid] = sdata[tid] - v;  // exclusive
  if (tid == 255) blocksums[blockIdx.x] = sdata[255];
}

// ---------------------------------------------------------------------------
// CSR build step 2b: add block offsets; emit rowptr and cursor.
// ---------------------------------------------------------------------------
__global__ __launch_bounds__(256) void scan_finalize_kernel(
    const int* __restrict__ prescan, const int* __restrict__ blocksums,
    int* __restrict__ rowptr, int* __restrict__ cursor) {
  __shared__ int sred[256];
  const int tid = threadIdx.x;
  int part = 0;
  for (int j = tid; j < blockIdx.x; j += 256) part += blocksums[j];
  sred[tid] = part;
  __syncthreads();
  for (int s = 128; s > 0; s >>= 1) {
    if (tid < s) sred[tid] += sred[tid + s];
    __syncthreads();
  }
  const int boff = sred[0];
  const int gid = blockIdx.x * 256 + tid;
  if (gid < N_NODES) {
    const int r = boff + prescan[gid];
    rowptr[gid] = r;
    cursor[gid] = r;
  }
  if (gid == 0) rowptr[N_NODES] = N_EDGES;
}

// ---------------------------------------------------------------------------
// CSR build step 3: place each edge's src into its dst bucket.
// ---------------------------------------------------------------------------
__global__ __launch_bounds__(256) void fill_kernel(const int* __restrict__ ei,
                                                   int* __restrict__ cursor,
                                                   int* __restrict__ srcs) {
  const int e = blockIdx.x * blockDim.x + threadIdx.x;
  if (e >= N_EDGES) return;
  const int d = ei[N_EDGES + e];
  const int pos = atomicAdd(&cursor[d], 1);
  srcs[pos] = ei[e];
}

// ---------------------------------------------------------------------------
// Cast x (f32) -> xb (bf16). 8 elems/thread.
// ---------------------------------------------------------------------------
__global__ __launch_bounds__(256) void cast_x_kernel(
    const float* __restrict__ x, unsigned short* __restrict__ xb) {
  const int t = blockIdx.x * blockDim.x + threadIdx.x;
  if (t >= (N_NODES * IN_CH) / 8) return;
  const float4 a = reinterpret_cast<const float4*>(x)[t * 2];
  const float4 c = reinterpret_cast<const float4*>(x)[t * 2 + 1];
  union { unsigned int u[4]; uint4 v; } o;
  o.u[0] = (unsigned)f2bf(a.x) | ((unsigned)f2bf(a.y) << 16);
  o.u[1] = (unsigned)f2bf(a.z) | ((unsigned)f2bf(a.w) << 16);
  o.u[2] = (unsigned)f2bf(c.x) | ((unsigned)f2bf(c.y) << 16);
  o.u[3] = (unsigned)f2bf(c.z) | ((unsigned)f2bf(c.w) << 16);
  reinterpret_cast<uint4*>(xb)[t] = o.v;
}

// ---------------------------------------------------------------------------
// W [OUT_CH, FEAT] f32 -> Wf bf16 in MFMA-fragment order:
// Wf[((kk*8+nt)*64 + lane)*8 + j] = W[nt*16+(lane&15)][kk*32+(lane>>4)*8+j]
// so the GEMM's B-frag load is one coalesced short8 per lane.
// ---------------------------------------------------------------------------
__global__ __launch_bounds__(256) void wfrag_kernel(
    const float* __restrict__ W, unsigned short* __restrict__ Wf) {
  const int t = blockIdx.x * blockDim.x + threadIdx.x;
  if (t >= 6 * 8 * 64 * 8) return;  // 24576 == FEAT*OUT_CH
  const int j = t & 7;
  const int l = (t >> 3) & 63;
  const int nt = (t >> 9) & 7;
  const int kk = t >> 12;
  const int o = nt * 16 + (l & 15);
  const int k = kk * 32 + (l >> 4) * 8 + j;
  Wf[t] = f2bf(W[o * FEAT + k]);
}

// ---------------------------------------------------------------------------
// Gather hop (bf16): hout[n][c] = sum over in-edges(n) of hin[src][c].
// One wave per node; lane = (g,s): g=lane>>3 picks edge slot (8 edges in
// flight), s=lane&7 picks 8-channel slice (uint4 = 8 bf16 = 16B).
// f32 accumulate, cross-group combine via shfl_xor, bf16 store by group 0.
// ---------------------------------------------------------------------------
__global__ __launch_bounds__(256) void gather_kernel(
    const unsigned short* __restrict__ hin, const int* __restrict__ rowptr,
    const int* __restrict__ srcs, unsigned short* __restrict__ hout) {
  const int gid = blockIdx.x * blockDim.x + threadIdx.x;
  const int node = gid >> 6;
  if (node >= N_NODES) return;
  const int lane = threadIdx.x & 63;
  const int g = lane >> 3;  // edge slot 0..7
  const int s = lane & 7;   // channel slice 0..7

  const int beg = rowptr[node];
  const int end = rowptr[node + 1];

  float acc[8];
#pragma unroll
  for (int j = 0; j < 8; ++j) acc[j] = 0.0f;

  for (int i = beg + g; i < end; i += 8) {
    const int src = srcs[i];
    const uint4 v = *reinterpret_cast<const uint4*>(
        hin + (size_t)src * IN_CH + s * 8);
    acc[0] += bf2f(v.x & 0xffffu); acc[1] += bf2f(v.x >> 16);
    acc[2] += bf2f(v.y & 0xffffu); acc[3] += bf2f(v.y >> 16);
    acc[4] += bf2f(v.z & 0xffffu); acc[5] += bf2f(v.z >> 16);
    acc[6] += bf2f(v.w & 0xffffu); acc[7] += bf2f(v.w >> 16);
  }

#pragma unroll
  for (int j = 0; j < 8; ++j) {
    acc[j] += __shfl_xor(acc[j], 8);
    acc[j] += __shfl_xor(acc[j], 16);
    acc[j] += __shfl_xor(acc[j], 32);
  }

  if (g == 0) {
    union { unsigned int u[4]; uint4 v; } o;
    o.u[0] = (unsigned)f2bf(acc[0]) | ((unsigned)f2bf(acc[1]) << 16);
    o.u[1] = (unsigned)f2bf(acc[2]) | ((unsigned)f2bf(acc[3]) << 16);
    o.u[2] = (unsigned)f2bf(acc[4]) | ((unsigned)f2bf(acc[5]) << 16);
    o.u[3] = (unsigned)f2bf(acc[6]) | ((unsigned)f2bf(acc[7]) << 16);
    *reinterpret_cast<uint4*>(hout + (size_t)node * IN_CH + s * 8) = o.v;
  }
}

// ---------------------------------------------------------------------------
// MFMA GEMM: out[n,o] = b[o] + [xb|h1b|h2b][n,:] @ W[o,:]  (bf16 in, f32 acc)
// One wave per 16-node tile; 8 n-tiles of 16 out-ch; K = 6 chunks of 32.
// A-frag: lane holds A[l&15][8*(l>>4)+j]; B-frag from pre-shuffled Wf.
// C/D (m89-verified): D[(l>>4)*4+r][l&15].
// ---------------------------------------------------------------------------
__global__ __launch_bounds__(256) void gemm_kernel(
    const unsigned short* __restrict__ xb,
    const unsigned short* __restrict__ h1b,
    const unsigned short* __restrict__ h2b,
    const unsigned short* __restrict__ Wf, const float* __restrict__ b,
    float* __restrict__ out) {
  const int wave = (blockIdx.x * 256 + threadIdx.x) >> 6;
  if (wave >= N_TILES) return;
  const int lane = threadIdx.x & 63;
  const int node0 = wave * 16;
  const int mrow = lane & 15;
  const int kg = lane >> 4;

  f32x4 acc[8];
#pragma unroll
  for (int nt = 0; nt < 8; ++nt) acc[nt] = (f32x4){0.f, 0.f, 0.f, 0.f};

  const unsigned short* const srcarr[3] = {xb, h1b, h2b};
#pragma unroll
  for (int kk = 0; kk < 6; ++kk) {
    const unsigned short* a = srcarr[kk >> 1];
    const short8 af = *reinterpret_cast<const short8*>(
        a + (size_t)(node0 + mrow) * IN_CH + (kk & 1) * 32 + kg * 8);
#pragma unroll
    for (int nt = 0; nt < 8; ++nt) {
      const short8 bf = *reinterpret_cast<const short8*>(
          Wf + ((size_t)(kk * 8 + nt) * 64 + lane) * 8);
      acc[nt] = __builtin_amdgcn_mfma_f32_16x16x32_bf16(af, bf, acc[nt], 0, 0, 0);
    }
  }

#pragma unroll
  for (int nt = 0; nt < 8; ++nt) {
    const int oc = nt * 16 + mrow;
    const float bias = b[oc];
#pragma unroll
    for (int r = 0; r < 4; ++r) {
      out[(size_t)(node0 + kg * 4 + r) * OUT_CH + oc] = acc[nt][r] + bias;
    }
  }
}

extern "C" void kernel_launch(void* const* d_in, const int* in_sizes, int n_in,
                              void* d_out, int out_size, void* d_ws,
                              size_t ws_size, hipStream_t stream) {
  const float* x = (const float*)d_in[0];
  const int* ei = (const int*)d_in[1];   // [2, N_EDGES], int32 per harness
  const float* W = (const float*)d_in[2];
  const float* b = (const float*)d_in[3];
  float* out = (float*)d_out;

  // Workspace layout (bytes): xb | h1b | h2b | Wf | counts | rowptr |
  //                           cursor | srcs | prescan | blocksums  (~23.7 MB)
  char* p = (char*)d_ws;
  unsigned short* xb = (unsigned short*)p;  p += (size_t)N_NODES * IN_CH * 2;
  unsigned short* h1b = (unsigned short*)p; p += (size_t)N_NODES * IN_CH * 2;
  unsigned short* h2b = (unsigned short*)p; p += (size_t)N_NODES * IN_CH * 2;
  unsigned short* Wf = (unsigned short*)p;  p += (size_t)FEAT * OUT_CH * 2;
  int* counts = (int*)p;  p += (size_t)N_NODES * 4;
  int* rowptr = (int*)p;  p += (size_t)(N_NODES + 1) * 4;
  int* cursor = (int*)p;  p += (size_t)N_NODES * 4;
  int* srcs = (int*)p;    p += (size_t)N_EDGES * 4;
  int* prescan = (int*)p; p += (size_t)N_NODES * 4;
  int* blocksums = (int*)p;

  // Zero only the histogram bins (ws is poisoned to 0xAA before every call).
  hipMemsetAsync(counts, 0, N_NODES * sizeof(int), stream);

  const int eblocks = (N_EDGES + 255) / 256;

  // Build by-destination CSR (int atomics only).
  hist_kernel<<<eblocks, 256, 0, stream>>>(ei, counts);
  scan_block_kernel<<<NBLK_SCAN, 256, 0, stream>>>(counts, prescan, blocksums);
  scan_finalize_kernel<<<NBLK_SCAN, 256, 0, stream>>>(prescan, blocksums,
                                                      rowptr, cursor);
  fill_kernel<<<eblocks, 256, 0, stream>>>(ei, cursor, srcs);

  // bf16 casts / weight fragment shuffle.
  cast_x_kernel<<<(N_NODES * IN_CH / 8 + 255) / 256, 256, 0, stream>>>(x, xb);
  wfrag_kernel<<<(FEAT * OUT_CH + 255) / 256, 256, 0, stream>>>(W, Wf);

  // Hop 1: h1 = gather(xb); Hop 2: h2 = gather(h1b). One wave per node.
  const int gblocks = (N_NODES * 64 + 255) / 256;
  gather_kernel<<<gblocks, 256, 0, stream>>>(xb, rowptr, srcs, h1b);
  gather_kernel<<<gblocks, 256, 0, stream>>>(h1b, rowptr, srcs, h2b);

  // out = [xb|h1b|h2b] @ W.T + b via MFMA.
  const int gemmblocks = (N_TILES + 3) / 4;  // 4 waves per block
  gemm_kernel<<<gemmblocks, 256, 0, stream>>>(xb, h1b, h2b, Wf, b, out);
}